// Round 1
// baseline (766.368 us; speedup 1.0000x reference)
//
#include <hip/hip_runtime.h>
#include <hip/hip_bf16.h>
#include <math.h>

#define NNODES 100000
#define NEDGES 600000
#define IN 128
#define HD 128   // NUM_HEADS * OUT_DIM
#define NH 8
#define DD 16
#define NEG_SLOPE 0.2f

// ---------------- helpers ----------------
__device__ inline void atomicMaxFloat(float* addr, float val) {
    // works for all finite floats and -inf init
    if (val >= 0.f) atomicMax((int*)addr, __float_as_int(val));
    else            atomicMin((unsigned int*)addr, __float_as_uint(val));
}

// ---------------- init: m = -inf, s = 0 ----------------
__global__ void k_init(float* __restrict__ m, float* __restrict__ s, int n) {
    int t = blockIdx.x * blockDim.x + threadIdx.x;
    if (t < n) {
        m[t] = __int_as_float(0xff800000);  // -inf
        s[t] = 0.f;
    }
}

// ---------------- GEMM z = h @ W  (+ el, er) ----------------
// block: 256 threads, 32 rows per block. W staged in LDS (64KB) + h tile (16KB).
__global__ __launch_bounds__(256) void k_gemm(
    const float* __restrict__ h, const float* __restrict__ W,
    const float* __restrict__ attn_l, const float* __restrict__ attn_r,
    float* __restrict__ z, float* __restrict__ el, float* __restrict__ er)
{
    __shared__ float Ws[IN][HD];   // 64 KB
    __shared__ float hs[32][IN];   // 16 KB
    const int tid = threadIdx.x;
    const int row0 = blockIdx.x * 32;

    // stage W
    const float4* W4 = (const float4*)W;
    float4* Ws4 = (float4*)&Ws[0][0];
    #pragma unroll
    for (int i = tid; i < IN * HD / 4; i += 256) Ws4[i] = W4[i];

    // stage h tile
    int nrows = NNODES - row0; if (nrows > 32) nrows = 32;
    const float4* h4 = (const float4*)(h + (size_t)row0 * IN);
    float4* hs4 = (float4*)&hs[0][0];
    for (int i = tid; i < nrows * IN / 4; i += 256) hs4[i] = h4[i];
    __syncthreads();

    const int c  = tid & 127;   // output column = hh*16+dd
    const int rg = tid >> 7;    // 0/1: row group of 16

    float acc[16];
    #pragma unroll
    for (int i = 0; i < 16; ++i) acc[i] = 0.f;

    for (int k = 0; k < IN; ++k) {
        float w = Ws[k][c];
        #pragma unroll
        for (int i = 0; i < 16; ++i)
            acc[i] = fmaf(hs[rg * 16 + i][k], w, acc[i]);
    }

    const int hh = c >> 4, dd = c & 15;
    const float al = attn_l[c];   // attn_l[hh][dd] flat = [c]
    const float ar = attn_r[c];

    #pragma unroll
    for (int i = 0; i < 16; ++i) {
        int r = row0 + rg * 16 + i;
        if (r < NNODES) {
            z[(size_t)r * HD + c] = acc[i];
            float vl = acc[i] * al;
            float vr = acc[i] * ar;
            // reduce over dd within aligned 16-lane group
            #pragma unroll
            for (int off = 8; off >= 1; off >>= 1) {
                vl += __shfl_xor(vl, off, 64);
                vr += __shfl_xor(vr, off, 64);
            }
            if (dd == 0) {
                el[r * NH + hh] = vl;
                er[r * NH + hh] = vr;
            }
        }
    }
}

// ---------------- edge pass 1: e = leakyrelu(el[dst]+er[src]); segment max ----------------
__global__ void k_edge1(const int* __restrict__ src, const int* __restrict__ dst,
                        const float* __restrict__ el, const float* __restrict__ er,
                        float* __restrict__ ebuf, float* __restrict__ m)
{
    int t = blockIdx.x * blockDim.x + threadIdx.x;
    if (t >= NEDGES * NH) return;
    int e  = t >> 3;
    int hh = t & 7;
    int d = dst[e], s = src[e];
    float v = el[d * NH + hh] + er[s * NH + hh];
    v = (v >= 0.f) ? v : NEG_SLOPE * v;
    ebuf[t] = v;
    atomicMaxFloat(&m[d * NH + hh], v);
}

// ---------------- edge pass 2: ex=exp(e-m); s+=ex; agg += ex*z[src] ----------------
// one 64-lane wave per edge; lane l covers columns 2l, 2l+1
__global__ __launch_bounds__(256) void k_edge2(
    const int* __restrict__ src, const int* __restrict__ dst,
    const float* __restrict__ ebuf, const float* __restrict__ m,
    const float* __restrict__ z, float* __restrict__ ssum, float* __restrict__ agg)
{
    int gid  = blockIdx.x * blockDim.x + threadIdx.x;
    int wid  = gid >> 6;          // edge id
    int lane = threadIdx.x & 63;
    if (wid >= NEDGES) return;
    int d = dst[wid], s = src[wid];
    int hh = lane >> 3;           // head of columns 2l,2l+1  ( (2l)/16 = l/8 )
    float ev = ebuf[wid * NH + hh];
    float mv = m[d * NH + hh];
    float ex = expf(ev - mv);
    if ((lane & 7) == 0) atomicAdd(&ssum[d * NH + hh], ex);
    float2 zv = ((const float2*)(z + (size_t)s * HD))[lane];
    atomicAdd(&agg[(size_t)d * HD + 2 * lane],     ex * zv.x);
    atomicAdd(&agg[(size_t)d * HD + 2 * lane + 1], ex * zv.y);
}

// ---------------- epilogue: out = o + elu(agg / s) ----------------
__global__ void k_final(const float* __restrict__ o, const float* __restrict__ ssum,
                        float* __restrict__ out)
{
    int t = blockIdx.x * blockDim.x + threadIdx.x;
    if (t >= NNODES * HD) return;
    int node = t >> 7;
    int c = t & 127;
    int hh = c >> 4;
    float sv = ssum[node * NH + hh];
    float a = (sv > 0.f) ? out[t] / sv : 0.f;   // empty segment -> agg 0, out = o
    float e = (a > 0.f) ? a : expm1f(a);
    out[t] = o[t] + e;
}

extern "C" void kernel_launch(void* const* d_in, const int* in_sizes, int n_in,
                              void* d_out, int out_size, void* d_ws, size_t ws_size,
                              hipStream_t stream) {
    const float* h      = (const float*)d_in[0];
    const float* o      = (const float*)d_in[1];
    const float* W      = (const float*)d_in[2];
    const float* attn_l = (const float*)d_in[3];
    const float* attn_r = (const float*)d_in[4];
    const int*   src    = (const int*)d_in[5];
    const int*   dst    = (const int*)d_in[6];
    float* out = (float*)d_out;

    char* ws = (char*)d_ws;
    float* z    = (float*)(ws);                         // N*128 = 51.2 MB
    float* el   = (float*)(ws + 51200000);              // N*8
    float* er   = (float*)(ws + 54400000);              // N*8
    float* m    = (float*)(ws + 57600000);              // N*8
    float* ssum = (float*)(ws + 60800000);              // N*8
    float* ebuf = (float*)(ws + 64000000);              // E*8 = 19.2 MB  (total 83.2 MB)

    // zero the aggregation accumulator (d_out) every call
    hipMemsetAsync(d_out, 0, (size_t)out_size * sizeof(float), stream);

    // init m=-inf, s=0
    {
        int n = NNODES * NH;
        k_init<<<(n + 255) / 256, 256, 0, stream>>>(m, ssum, n);
    }
    // GEMM + logit halves
    k_gemm<<<(NNODES + 31) / 32, 256, 0, stream>>>(h, W, attn_l, attn_r, z, el, er);
    // edge pass 1
    {
        int n = NEDGES * NH;
        k_edge1<<<(n + 255) / 256, 256, 0, stream>>>(src, dst, el, er, ebuf, m);
    }
    // edge pass 2 (one wave per edge)
    {
        long long threads = (long long)NEDGES * 64;
        k_edge2<<<(int)((threads + 255) / 256), 256, 0, stream>>>(src, dst, ebuf, m, z, ssum, out);
    }
    // epilogue
    {
        int n = NNODES * HD;
        k_final<<<(n + 255) / 256, 256, 0, stream>>>(o, ssum, out);
    }
}

// Round 2
// 324.198 us; speedup vs baseline: 2.3639x; 2.3639x over previous
//
#include <hip/hip_runtime.h>
#include <hip/hip_bf16.h>
#include <math.h>

#define NNODES 100000
#define NEDGES 600000
#define IN 128
#define HD 128   // NUM_HEADS * OUT_DIM
#define NH 8
#define NEG_SLOPE 0.2f

// ---------------- GEMM z = h @ W  (+ el, er) ----------------
// block: 256 threads, 32 rows per block. W staged in LDS (64KB) + h tile (16KB).
__global__ __launch_bounds__(256) void k_gemm(
    const float* __restrict__ h, const float* __restrict__ W,
    const float* __restrict__ attn_l, const float* __restrict__ attn_r,
    float* __restrict__ z, float* __restrict__ el, float* __restrict__ er)
{
    __shared__ float Ws[IN][HD];   // 64 KB
    __shared__ float hs[32][IN];   // 16 KB
    const int tid = threadIdx.x;
    const int row0 = blockIdx.x * 32;

    // stage W
    const float4* W4 = (const float4*)W;
    float4* Ws4 = (float4*)&Ws[0][0];
    #pragma unroll
    for (int i = tid; i < IN * HD / 4; i += 256) Ws4[i] = W4[i];

    // stage h tile
    int nrows = NNODES - row0; if (nrows > 32) nrows = 32;
    const float4* h4 = (const float4*)(h + (size_t)row0 * IN);
    float4* hs4 = (float4*)&hs[0][0];
    for (int i = tid; i < nrows * IN / 4; i += 256) hs4[i] = h4[i];
    __syncthreads();

    const int c  = tid & 127;   // output column = hh*16+dd
    const int rg = tid >> 7;    // 0/1: row group of 16

    float acc[16];
    #pragma unroll
    for (int i = 0; i < 16; ++i) acc[i] = 0.f;

    for (int k = 0; k < IN; ++k) {
        float w = Ws[k][c];
        #pragma unroll
        for (int i = 0; i < 16; ++i)
            acc[i] = fmaf(hs[rg * 16 + i][k], w, acc[i]);
    }

    const int hh = c >> 4, dd = c & 15;
    const float al = attn_l[c];
    const float ar = attn_r[c];

    #pragma unroll
    for (int i = 0; i < 16; ++i) {
        int r = row0 + rg * 16 + i;
        if (r < NNODES) {
            z[(size_t)r * HD + c] = acc[i];
            float vl = acc[i] * al;
            float vr = acc[i] * ar;
            #pragma unroll
            for (int off = 8; off >= 1; off >>= 1) {
                vl += __shfl_xor(vl, off, 64);
                vr += __shfl_xor(vr, off, 64);
            }
            if (dd == 0) {
                el[r * NH + hh] = vl;
                er[r * NH + hh] = vr;
            }
        }
    }
}

// ---------------- CSR build ----------------
__global__ void k_hist(const int* __restrict__ dst, int* __restrict__ cnt) {
    int e = blockIdx.x * blockDim.x + threadIdx.x;
    if (e >= NEDGES) return;
    atomicAdd(&cnt[dst[e]], 1);
}

// per-block inclusive scan (Hillis-Steele over 1024)
__global__ __launch_bounds__(1024) void kscan1(const int* __restrict__ cnt,
                                               int* __restrict__ inc, int* __restrict__ bsum) {
    __shared__ int buf[2][1024];
    int t = threadIdx.x;
    int i = blockIdx.x * 1024 + t;
    int v = (i < NNODES) ? cnt[i] : 0;
    buf[0][t] = v; __syncthreads();
    int cur = 0;
    for (int off = 1; off < 1024; off <<= 1) {
        int nv = buf[cur][t];
        if (t >= off) nv += buf[cur][t - off];
        buf[cur ^ 1][t] = nv; __syncthreads();
        cur ^= 1;
    }
    if (i < NNODES) inc[i] = buf[cur][t];
    if (t == 1023) bsum[blockIdx.x] = buf[cur][1023];
}

// exclusive scan of the (<=128) block sums, in place
__global__ __launch_bounds__(128) void kscan2(int* __restrict__ bsum, int n) {
    __shared__ int buf[2][128];
    int t = threadIdx.x;
    int v = (t < n) ? bsum[t] : 0;
    buf[0][t] = v; __syncthreads();
    int cur = 0;
    for (int off = 1; off < 128; off <<= 1) {
        int nv = buf[cur][t];
        if (t >= off) nv += buf[cur][t - off];
        buf[cur ^ 1][t] = nv; __syncthreads();
        cur ^= 1;
    }
    if (t < n) bsum[t] = buf[cur][t] - v;
}

__global__ __launch_bounds__(1024) void kscan3(const int* __restrict__ cnt, const int* __restrict__ inc,
                                               const int* __restrict__ bsum,
                                               int* __restrict__ offs, int* __restrict__ cursor) {
    int t = threadIdx.x;
    int i = blockIdx.x * 1024 + t;
    if (i < NNODES) {
        int ex = inc[i] - cnt[i] + bsum[blockIdx.x];
        offs[i] = ex;
        cursor[i] = ex;
    }
    if (i == 0) offs[NNODES] = NEDGES;
}

__global__ void k_scatter(const int* __restrict__ src, const int* __restrict__ dst,
                          int* __restrict__ cursor, int* __restrict__ esrc) {
    int e = blockIdx.x * blockDim.x + threadIdx.x;
    if (e >= NEDGES) return;
    int d = dst[e];
    int pos = atomicAdd(&cursor[d], 1);
    esrc[pos] = src[e];
}

// ---------------- aggregate: one wave per destination node ----------------
// lane l covers columns 2l, 2l+1; head hh = l>>3 (8 lanes per head)
__global__ __launch_bounds__(256) void k_agg(
    const int* __restrict__ offs, const int* __restrict__ esrc,
    const float* __restrict__ el, const float* __restrict__ er,
    const float* __restrict__ z, const float* __restrict__ o,
    float* __restrict__ out)
{
    int wid  = (blockIdx.x * blockDim.x + threadIdx.x) >> 6;
    int lane = threadIdx.x & 63;
    if (wid >= NNODES) return;
    const int d = wid;
    const int p0 = offs[d], p1 = offs[d + 1];
    const int hh = lane >> 3;
    const float el8 = el[d * NH + hh];

    // pass 1: per-head max (uniform across the 8 lanes of a head)
    float mx = -INFINITY;
    for (int p = p0; p < p1; ++p) {
        int s = esrc[p];
        float ev = el8 + er[s * NH + hh];
        ev = (ev >= 0.f) ? ev : NEG_SLOPE * ev;
        mx = fmaxf(mx, ev);
    }

    // pass 2: exp + weighted aggregation of z[src]
    float srun = 0.f, a0 = 0.f, a1 = 0.f;
    for (int p = p0; p < p1; ++p) {
        int s = esrc[p];
        float ev = el8 + er[s * NH + hh];
        ev = (ev >= 0.f) ? ev : NEG_SLOPE * ev;
        float ex = expf(ev - mx);
        srun += ex;
        float2 zv = ((const float2*)(z + (size_t)s * HD))[lane];
        a0 = fmaf(ex, zv.x, a0);
        a1 = fmaf(ex, zv.y, a1);
    }

    const size_t base = (size_t)d * HD + 2 * lane;
    float inv = (srun > 0.f) ? 1.f / srun : 0.f;
    float r0 = a0 * inv, r1 = a1 * inv;
    r0 = (r0 > 0.f) ? r0 : expm1f(r0);
    r1 = (r1 > 0.f) ? r1 : expm1f(r1);
    out[base]     = o[base]     + r0;
    out[base + 1] = o[base + 1] + r1;
}

extern "C" void kernel_launch(void* const* d_in, const int* in_sizes, int n_in,
                              void* d_out, int out_size, void* d_ws, size_t ws_size,
                              hipStream_t stream) {
    const float* h      = (const float*)d_in[0];
    const float* o      = (const float*)d_in[1];
    const float* W      = (const float*)d_in[2];
    const float* attn_l = (const float*)d_in[3];
    const float* attn_r = (const float*)d_in[4];
    const int*   src    = (const int*)d_in[5];
    const int*   dst    = (const int*)d_in[6];
    float* out = (float*)d_out;

    char* ws = (char*)d_ws;
    float* z      = (float*)(ws);                      // 51,200,000 B
    float* el     = (float*)(ws + 51200000);           //  3,200,000
    float* er     = (float*)(ws + 54400000);           //  3,200,000
    int*   cnt    = (int*)  (ws + 57600000);           //    400,000
    int*   inc    = (int*)  (ws + 58000000);           //    400,000
    int*   offs   = (int*)  (ws + 58400000);           //    400,016
    int*   cursor = (int*)  (ws + 58800016);           //    400,000
    int*   bsum   = (int*)  (ws + 59200016);           //        512
    int*   esrc   = (int*)  (ws + 59200528);           //  2,400,000  (end ~61.6 MB)

    const int SCAN_BLOCKS = (NNODES + 1023) / 1024;    // 98

    hipMemsetAsync(cnt, 0, NNODES * sizeof(int), stream);

    k_gemm<<<(NNODES + 31) / 32, 256, 0, stream>>>(h, W, attn_l, attn_r, z, el, er);

    k_hist<<<(NEDGES + 255) / 256, 256, 0, stream>>>(dst, cnt);
    kscan1<<<SCAN_BLOCKS, 1024, 0, stream>>>(cnt, inc, bsum);
    kscan2<<<1, 128, 0, stream>>>(bsum, SCAN_BLOCKS);
    kscan3<<<SCAN_BLOCKS, 1024, 0, stream>>>(cnt, inc, bsum, offs, cursor);
    k_scatter<<<(NEDGES + 255) / 256, 256, 0, stream>>>(src, dst, cursor, esrc);

    k_agg<<<(NNODES * 64 + 255) / 256, 256, 0, stream>>>(offs, esrc, el, er, z, o, out);
}

// Round 3
// 217.870 us; speedup vs baseline: 3.5175x; 1.4880x over previous
//
#include <hip/hip_runtime.h>
#include <hip/hip_bf16.h>
#include <math.h>

#define NNODES 100000
#define NEDGES 600000
#define IN 128
#define HD 128   // NUM_HEADS * OUT_DIM
#define NH 8
#define NEG_SLOPE 0.2f
#define RG_TOTAL (NNODES / 16)   // 6250 row-groups of 16 (exact)
#define NFRAG 36                 // 4 K-steps * 9 col-tiles
#define CT_ALL 9                 // 8 z col-tiles + 1 [el|er] tile

typedef __attribute__((ext_vector_type(8))) short short8v;
typedef __attribute__((ext_vector_type(4))) float f32x4;

__device__ inline unsigned short f2bf(float f) {
    unsigned u = __float_as_uint(f);
    unsigned r = (u + 0x7fff + ((u >> 16) & 1)) >> 16;
    return (unsigned short)r;
}
__device__ inline float bflo(unsigned v) { return __uint_as_float(v << 16); }
__device__ inline float bfhi(unsigned v) { return __uint_as_float(v & 0xffff0000u); }

// ---------------- pack W (+ fused Wl/Wr logit columns) into MFMA fragment order ----------------
// Wb[(ks*9+ct)*64 + lane] = short8v, elem j:
//   ct<8 : W[ks*32 + (lane>>4)*8 + j][ct*16 + (lane&15)]
//   ct==8: col c=lane&15; c<8 -> Wl[k][c] = sum_d W[k][c*16+d]*attn_l[c*16+d]
//                         c>=8 -> Wr[k][c-8]
__global__ __launch_bounds__(256) void k_pack(
    const float* __restrict__ W, const float* __restrict__ attn_l, const float* __restrict__ attn_r,
    short8v* __restrict__ Wb)
{
    int t = threadIdx.x;
    for (int slot = t; slot < NFRAG * 64; slot += 256) {
        int f = slot >> 6, lane = slot & 63;
        int ks = f / CT_ALL, ct = f % CT_ALL;
        int k0 = ks * 32 + (lane >> 4) * 8;
        short8v v;
        if (ct < 8) {
            int col = ct * 16 + (lane & 15);
            #pragma unroll
            for (int j = 0; j < 8; ++j) v[j] = (short)f2bf(W[(k0 + j) * HD + col]);
        } else {
            int c = lane & 15;
            const float* av = (c < 8) ? attn_l : attn_r;
            int hh = c & 7;
            #pragma unroll
            for (int j = 0; j < 8; ++j) {
                int k = k0 + j;
                float s = 0.f;
                for (int d = 0; d < 16; ++d) s += W[k * HD + hh * 16 + d] * av[hh * 16 + d];
                v[j] = (short)f2bf(s);
            }
        }
        Wb[slot] = v;
    }
}

// ---------------- MFMA GEMM: z = h@W (bf16 out) + el/er ----------------
__global__ __launch_bounds__(256) void k_gemm_mfma(
    const float* __restrict__ h, const short8v* __restrict__ Wb,
    unsigned short* __restrict__ z, float* __restrict__ el, float* __restrict__ er)
{
    __shared__ short8v Bs[NFRAG * 64];   // 36 KB
    const int tid = threadIdx.x;
    {
        const float4* srcp = (const float4*)Wb;
        float4* dstp = (float4*)Bs;
        for (int i = tid; i < NFRAG * 64; i += 256) dstp[i] = srcp[i];
    }
    __syncthreads();

    const int lane  = tid & 63;
    const int rowIn = lane & 15;    // A row within group / C col within tile
    const int kgrp  = lane >> 4;    // A k-group / C row-group
    int wid = (blockIdx.x * 256 + tid) >> 6;
    const int nw = gridDim.x * 4;

    for (int rg = wid; rg < RG_TOTAL; rg += nw) {
        const int row0 = rg * 16;
        const float* hp = h + (size_t)(row0 + rowIn) * IN + kgrp * 8;

        short8v afr[4];
        #pragma unroll
        for (int ks = 0; ks < 4; ++ks) {
            float4 a0 = *(const float4*)(hp + ks * 32);
            float4 a1 = *(const float4*)(hp + ks * 32 + 4);
            short8v v;
            v[0] = (short)f2bf(a0.x); v[1] = (short)f2bf(a0.y);
            v[2] = (short)f2bf(a0.z); v[3] = (short)f2bf(a0.w);
            v[4] = (short)f2bf(a1.x); v[5] = (short)f2bf(a1.y);
            v[6] = (short)f2bf(a1.z); v[7] = (short)f2bf(a1.w);
            afr[ks] = v;
        }

        f32x4 acc[CT_ALL];
        #pragma unroll
        for (int ct = 0; ct < CT_ALL; ++ct) acc[ct] = (f32x4){0.f, 0.f, 0.f, 0.f};

        #pragma unroll
        for (int ks = 0; ks < 4; ++ks)
            #pragma unroll
            for (int ct = 0; ct < CT_ALL; ++ct)
                acc[ct] = __builtin_amdgcn_mfma_f32_16x16x32_bf16(
                    afr[ks], Bs[(ks * CT_ALL + ct) * 64 + lane], acc[ct], 0, 0, 0);

        const int rbase = row0 + kgrp * 4;
        #pragma unroll
        for (int ct = 0; ct < 8; ++ct)
            #pragma unroll
            for (int r = 0; r < 4; ++r)
                z[(size_t)(rbase + r) * HD + ct * 16 + rowIn] = f2bf(acc[ct][r]);

        #pragma unroll
        for (int r = 0; r < 4; ++r) {
            float v = acc[8][r];
            int row = rbase + r;
            if (rowIn < 8) el[row * NH + rowIn] = v;
            else           er[row * NH + rowIn - 8] = v;
        }
    }
}

// ---------------- CSR build ----------------
__global__ void k_hist(const int* __restrict__ dst, int* __restrict__ cnt) {
    int e = blockIdx.x * blockDim.x + threadIdx.x;
    if (e >= NEDGES) return;
    atomicAdd(&cnt[dst[e]], 1);
}

__global__ __launch_bounds__(1024) void kscan1(const int* __restrict__ cnt,
                                               int* __restrict__ inc, int* __restrict__ bsum) {
    __shared__ int buf[2][1024];
    int t = threadIdx.x;
    int i = blockIdx.x * 1024 + t;
    int v = (i < NNODES) ? cnt[i] : 0;
    buf[0][t] = v; __syncthreads();
    int cur = 0;
    for (int off = 1; off < 1024; off <<= 1) {
        int nv = buf[cur][t];
        if (t >= off) nv += buf[cur][t - off];
        buf[cur ^ 1][t] = nv; __syncthreads();
        cur ^= 1;
    }
    if (i < NNODES) inc[i] = buf[cur][t];
    if (t == 1023) bsum[blockIdx.x] = buf[cur][1023];
}

__global__ __launch_bounds__(128) void kscan2(int* __restrict__ bsum, int n) {
    __shared__ int buf[2][128];
    int t = threadIdx.x;
    int v = (t < n) ? bsum[t] : 0;
    buf[0][t] = v; __syncthreads();
    int cur = 0;
    for (int off = 1; off < 128; off <<= 1) {
        int nv = buf[cur][t];
        if (t >= off) nv += buf[cur][t - off];
        buf[cur ^ 1][t] = nv; __syncthreads();
        cur ^= 1;
    }
    if (t < n) bsum[t] = buf[cur][t] - v;
}

__global__ __launch_bounds__(1024) void kscan3(const int* __restrict__ cnt, const int* __restrict__ inc,
                                               const int* __restrict__ bsum,
                                               int* __restrict__ offs, int* __restrict__ cursor) {
    int t = threadIdx.x;
    int i = blockIdx.x * 1024 + t;
    if (i < NNODES) {
        int ex = inc[i] - cnt[i] + bsum[blockIdx.x];
        offs[i] = ex;
        cursor[i] = ex;
    }
    if (i == 0) offs[NNODES] = NEDGES;
}

__global__ void k_scatter(const int* __restrict__ src, const int* __restrict__ dst,
                          int* __restrict__ cursor, int* __restrict__ esrc) {
    int e = blockIdx.x * blockDim.x + threadIdx.x;
    if (e >= NEDGES) return;
    int d = dst[e];
    int pos = atomicAdd(&cursor[d], 1);
    esrc[pos] = src[e];
}

// ---------------- aggregate: one wave per destination node ----------------
// lane l covers columns 2l, 2l+1; head hh = l>>3
__global__ __launch_bounds__(256) void k_agg(
    const int* __restrict__ offs, const int* __restrict__ esrc,
    const float* __restrict__ el, const float* __restrict__ er,
    const unsigned short* __restrict__ z, const float* __restrict__ o,
    float* __restrict__ out)
{
    int wid  = (blockIdx.x * blockDim.x + threadIdx.x) >> 6;
    int lane = threadIdx.x & 63;
    if (wid >= NNODES) return;
    const int d = wid;
    const int p0 = offs[d], p1 = offs[d + 1];
    const int hh = lane >> 3;
    const float el8 = el[d * NH + hh];

    float mx = -INFINITY;
    for (int p = p0; p < p1; ++p) {
        int s = esrc[p];
        float ev = el8 + er[s * NH + hh];
        ev = (ev >= 0.f) ? ev : NEG_SLOPE * ev;
        mx = fmaxf(mx, ev);
    }

    float srun = 0.f, a0 = 0.f, a1 = 0.f;
    for (int p = p0; p < p1; ++p) {
        int s = esrc[p];
        float ev = el8 + er[s * NH + hh];
        ev = (ev >= 0.f) ? ev : NEG_SLOPE * ev;
        float ex = expf(ev - mx);
        srun += ex;
        unsigned zb = ((const unsigned*)(z + (size_t)s * HD))[lane];
        a0 = fmaf(ex, bflo(zb), a0);
        a1 = fmaf(ex, bfhi(zb), a1);
    }

    const size_t base = (size_t)d * HD + 2 * lane;
    float inv = (srun > 0.f) ? 1.f / srun : 0.f;
    float r0 = a0 * inv, r1 = a1 * inv;
    r0 = (r0 > 0.f) ? r0 : expm1f(r0);
    r1 = (r1 > 0.f) ? r1 : expm1f(r1);
    out[base]     = o[base]     + r0;
    out[base + 1] = o[base + 1] + r1;
}

extern "C" void kernel_launch(void* const* d_in, const int* in_sizes, int n_in,
                              void* d_out, int out_size, void* d_ws, size_t ws_size,
                              hipStream_t stream) {
    const float* h      = (const float*)d_in[0];
    const float* o      = (const float*)d_in[1];
    const float* W      = (const float*)d_in[2];
    const float* attn_l = (const float*)d_in[3];
    const float* attn_r = (const float*)d_in[4];
    const int*   src    = (const int*)d_in[5];
    const int*   dst    = (const int*)d_in[6];
    float* out = (float*)d_out;

    char* ws = (char*)d_ws;
    unsigned short* z = (unsigned short*)(ws);         // 25,600,000 B (bf16)
    float* el     = (float*)(ws + 25600000);           //  3,200,000
    float* er     = (float*)(ws + 28800000);           //  3,200,000
    int*   cnt    = (int*)  (ws + 32000000);           //    400,000
    int*   inc    = (int*)  (ws + 32400000);           //    400,000
    int*   offs   = (int*)  (ws + 32800000);           //    400,016
    int*   cursor = (int*)  (ws + 33200016);           //    400,000
    int*   bsum   = (int*)  (ws + 33600016);           //        512
    int*   esrc   = (int*)  (ws + 33600528);           //  2,400,000
    short8v* Wb   = (short8v*)(ws + 36000528);         //     36,864  (end ~36.04 MB)

    const int SCAN_BLOCKS = (NNODES + 1023) / 1024;    // 98

    hipMemsetAsync(cnt, 0, NNODES * sizeof(int), stream);

    k_pack<<<1, 256, 0, stream>>>(W, attn_l, attn_r, Wb);
    k_gemm_mfma<<<512, 256, 0, stream>>>(h, Wb, z, el, er);

    k_hist<<<(NEDGES + 255) / 256, 256, 0, stream>>>(dst, cnt);
    kscan1<<<SCAN_BLOCKS, 1024, 0, stream>>>(cnt, inc, bsum);
    kscan2<<<1, 128, 0, stream>>>(bsum, SCAN_BLOCKS);
    kscan3<<<SCAN_BLOCKS, 1024, 0, stream>>>(cnt, inc, bsum, offs, cursor);
    k_scatter<<<(NEDGES + 255) / 256, 256, 0, stream>>>(src, dst, cursor, esrc);

    k_agg<<<(NNODES * 64 + 255) / 256, 256, 0, stream>>>(offs, esrc, el, er, z, o, out);
}

// Round 4
// 177.524 us; speedup vs baseline: 4.3170x; 1.2273x over previous
//
#include <hip/hip_runtime.h>
#include <hip/hip_bf16.h>
#include <math.h>

#define NNODES 100000
#define NEDGES 600000
#define IN 128
#define HD 128   // NUM_HEADS * OUT_DIM
#define NH 8
#define NEG_SLOPE 0.2f
#define RG_TOTAL (NNODES / 16)   // 6250 row-groups of 16 (exact)
#define NFRAG 36                 // 4 K-steps * 9 col-tiles
#define CT_ALL 9                 // 8 z col-tiles + 1 [el|er] tile

typedef __attribute__((ext_vector_type(8))) short short8v;
typedef __attribute__((ext_vector_type(4))) float f32x4;

__device__ inline unsigned short f2bf(float f) {
    unsigned u = __float_as_uint(f);
    unsigned r = (u + 0x7fff + ((u >> 16) & 1)) >> 16;
    return (unsigned short)r;
}
__device__ inline float bflo(unsigned v) { return __uint_as_float(v << 16); }
__device__ inline float bfhi(unsigned v) { return __uint_as_float(v & 0xffff0000u); }

// ---------------- pack W (+ fused Wl/Wr logit columns) into MFMA fragment order ----------------
__global__ __launch_bounds__(256) void k_pack(
    const float* __restrict__ W, const float* __restrict__ attn_l, const float* __restrict__ attn_r,
    short8v* __restrict__ Wb)
{
    int t = threadIdx.x;
    for (int slot = t; slot < NFRAG * 64; slot += 256) {
        int f = slot >> 6, lane = slot & 63;
        int ks = f / CT_ALL, ct = f % CT_ALL;
        int k0 = ks * 32 + (lane >> 4) * 8;
        short8v v;
        if (ct < 8) {
            int col = ct * 16 + (lane & 15);
            #pragma unroll
            for (int j = 0; j < 8; ++j) v[j] = (short)f2bf(W[(k0 + j) * HD + col]);
        } else {
            int c = lane & 15;
            const float* av = (c < 8) ? attn_l : attn_r;
            int hh = c & 7;
            #pragma unroll
            for (int j = 0; j < 8; ++j) {
                int k = k0 + j;
                float s = 0.f;
                for (int d = 0; d < 16; ++d) s += W[k * HD + hh * 16 + d] * av[hh * 16 + d];
                v[j] = (short)f2bf(s);
            }
        }
        Wb[slot] = v;
    }
}

// ---------------- MFMA GEMM: z = h@W (bf16 out) + el/er ----------------
__global__ __launch_bounds__(256) void k_gemm_mfma(
    const float* __restrict__ h, const short8v* __restrict__ Wb,
    unsigned short* __restrict__ z, float* __restrict__ el, float* __restrict__ er)
{
    __shared__ short8v Bs[NFRAG * 64];   // 36 KB
    const int tid = threadIdx.x;
    {
        const float4* srcp = (const float4*)Wb;
        float4* dstp = (float4*)Bs;
        for (int i = tid; i < NFRAG * 64; i += 256) dstp[i] = srcp[i];
    }
    __syncthreads();

    const int lane  = tid & 63;
    const int rowIn = lane & 15;
    const int kgrp  = lane >> 4;
    int wid = (blockIdx.x * 256 + tid) >> 6;
    const int nw = gridDim.x * 4;

    for (int rg = wid; rg < RG_TOTAL; rg += nw) {
        const int row0 = rg * 16;
        const float* hp = h + (size_t)(row0 + rowIn) * IN + kgrp * 8;

        short8v afr[4];
        #pragma unroll
        for (int ks = 0; ks < 4; ++ks) {
            float4 a0 = *(const float4*)(hp + ks * 32);
            float4 a1 = *(const float4*)(hp + ks * 32 + 4);
            short8v v;
            v[0] = (short)f2bf(a0.x); v[1] = (short)f2bf(a0.y);
            v[2] = (short)f2bf(a0.z); v[3] = (short)f2bf(a0.w);
            v[4] = (short)f2bf(a1.x); v[5] = (short)f2bf(a1.y);
            v[6] = (short)f2bf(a1.z); v[7] = (short)f2bf(a1.w);
            afr[ks] = v;
        }

        f32x4 acc[CT_ALL];
        #pragma unroll
        for (int ct = 0; ct < CT_ALL; ++ct) acc[ct] = (f32x4){0.f, 0.f, 0.f, 0.f};

        #pragma unroll
        for (int ks = 0; ks < 4; ++ks)
            #pragma unroll
            for (int ct = 0; ct < CT_ALL; ++ct)
                acc[ct] = __builtin_amdgcn_mfma_f32_16x16x32_bf16(
                    afr[ks], Bs[(ks * CT_ALL + ct) * 64 + lane], acc[ct], 0, 0, 0);

        const int rbase = row0 + kgrp * 4;
        #pragma unroll
        for (int ct = 0; ct < 8; ++ct)
            #pragma unroll
            for (int r = 0; r < 4; ++r)
                z[(size_t)(rbase + r) * HD + ct * 16 + rowIn] = f2bf(acc[ct][r]);

        #pragma unroll
        for (int r = 0; r < 4; ++r) {
            float v = acc[8][r];
            int row = rbase + r;
            if (rowIn < 8) el[row * NH + rowIn] = v;
            else           er[row * NH + rowIn - 8] = v;
        }
    }
}

// ---------------- CSR build ----------------
__global__ void k_hist(const int* __restrict__ dst, int* __restrict__ cnt) {
    int e = blockIdx.x * blockDim.x + threadIdx.x;
    if (e >= NEDGES) return;
    atomicAdd(&cnt[dst[e]], 1);
}

__global__ __launch_bounds__(1024) void kscan1(const int* __restrict__ cnt,
                                               int* __restrict__ inc, int* __restrict__ bsum) {
    __shared__ int buf[2][1024];
    int t = threadIdx.x;
    int i = blockIdx.x * 1024 + t;
    int v = (i < NNODES) ? cnt[i] : 0;
    buf[0][t] = v; __syncthreads();
    int cur = 0;
    for (int off = 1; off < 1024; off <<= 1) {
        int nv = buf[cur][t];
        if (t >= off) nv += buf[cur][t - off];
        buf[cur ^ 1][t] = nv; __syncthreads();
        cur ^= 1;
    }
    if (i < NNODES) inc[i] = buf[cur][t];
    if (t == 1023) bsum[blockIdx.x] = buf[cur][1023];
}

__global__ __launch_bounds__(128) void kscan2(int* __restrict__ bsum, int n) {
    __shared__ int buf[2][128];
    int t = threadIdx.x;
    int v = (t < n) ? bsum[t] : 0;
    buf[0][t] = v; __syncthreads();
    int cur = 0;
    for (int off = 1; off < 128; off <<= 1) {
        int nv = buf[cur][t];
        if (t >= off) nv += buf[cur][t - off];
        buf[cur ^ 1][t] = nv; __syncthreads();
        cur ^= 1;
    }
    if (t < n) bsum[t] = buf[cur][t] - v;
}

__global__ __launch_bounds__(1024) void kscan3(const int* __restrict__ cnt, const int* __restrict__ inc,
                                               const int* __restrict__ bsum,
                                               int* __restrict__ offs, int* __restrict__ cursor) {
    int t = threadIdx.x;
    int i = blockIdx.x * 1024 + t;
    if (i < NNODES) {
        int ex = inc[i] - cnt[i] + bsum[blockIdx.x];
        offs[i] = ex;
        cursor[i] = ex;
    }
    if (i == 0) offs[NNODES] = NEDGES;
}

__global__ void k_scatter(const int* __restrict__ src, const int* __restrict__ dst,
                          int* __restrict__ cursor, int* __restrict__ esrc) {
    int e = blockIdx.x * blockDim.x + threadIdx.x;
    if (e >= NEDGES) return;
    int d = dst[e];
    int pos = atomicAdd(&cursor[d], 1);
    esrc[pos] = src[e];
}

// ---------------- aggregate: one wave per destination node ----------------
// single pass (no segment-max: it cancels in alpha); software-pipelined prefetch
__global__ __launch_bounds__(256) void k_agg(
    const int* __restrict__ offs, const int* __restrict__ esrc,
    const float* __restrict__ el, const float* __restrict__ er,
    const unsigned short* __restrict__ z, const float* __restrict__ o,
    float* __restrict__ out)
{
    int wid  = (blockIdx.x * blockDim.x + threadIdx.x) >> 6;
    int lane = threadIdx.x & 63;
    if (wid >= NNODES) return;
    const int d = wid;
    const int p0 = offs[d];
    const int n  = offs[d + 1] - p0;
    const int hh = lane >> 3;
    const float el8 = el[d * NH + hh];

    float srun = 0.f, a0 = 0.f, a1 = 0.f;

    if (n > 0) {
        // prologue: current edge data + next edge id
        int s_cur = esrc[p0];
        float erv = er[s_cur * NH + hh];
        unsigned zb = ((const unsigned*)(z + (size_t)s_cur * HD))[lane];
        int s_nxt = (n > 1) ? esrc[p0 + 1] : 0;

        for (int i = 0; i < n; ++i) {
            // issue next-next id and next data loads before consuming current
            int s_nn = (i + 2 < n) ? esrc[p0 + i + 2] : 0;
            float ern = 0.f; unsigned zbn = 0;
            if (i + 1 < n) {
                ern = er[s_nxt * NH + hh];
                zbn = ((const unsigned*)(z + (size_t)s_nxt * HD))[lane];
            }
            float ev = el8 + erv;
            ev = (ev >= 0.f) ? ev : NEG_SLOPE * ev;
            float ex = __expf(ev);
            srun += ex;
            a0 = fmaf(ex, bflo(zb), a0);
            a1 = fmaf(ex, bfhi(zb), a1);
            erv = ern; zb = zbn; s_nxt = s_nn;
        }
    }

    const size_t base = (size_t)d * HD + 2 * lane;
    float inv = (srun > 0.f) ? 1.f / srun : 0.f;
    float r0 = a0 * inv, r1 = a1 * inv;
    r0 = (r0 > 0.f) ? r0 : expm1f(r0);
    r1 = (r1 > 0.f) ? r1 : expm1f(r1);
    out[base]     = o[base]     + r0;
    out[base + 1] = o[base + 1] + r1;
}

extern "C" void kernel_launch(void* const* d_in, const int* in_sizes, int n_in,
                              void* d_out, int out_size, void* d_ws, size_t ws_size,
                              hipStream_t stream) {
    const float* h      = (const float*)d_in[0];
    const float* o      = (const float*)d_in[1];
    const float* W      = (const float*)d_in[2];
    const float* attn_l = (const float*)d_in[3];
    const float* attn_r = (const float*)d_in[4];
    const int*   src    = (const int*)d_in[5];
    const int*   dst    = (const int*)d_in[6];
    float* out = (float*)d_out;

    char* ws = (char*)d_ws;
    unsigned short* z = (unsigned short*)(ws);         // 25,600,000 B (bf16)
    float* el     = (float*)(ws + 25600000);           //  3,200,000
    float* er     = (float*)(ws + 28800000);           //  3,200,000
    int*   cnt    = (int*)  (ws + 32000000);           //    400,000
    int*   inc    = (int*)  (ws + 32400000);           //    400,000
    int*   offs   = (int*)  (ws + 32800000);           //    400,016
    int*   cursor = (int*)  (ws + 33200016);           //    400,000
    int*   bsum   = (int*)  (ws + 33600016);           //        512
    int*   esrc   = (int*)  (ws + 33600528);           //  2,400,000
    short8v* Wb   = (short8v*)(ws + 36000528);         //     36,864

    const int SCAN_BLOCKS = (NNODES + 1023) / 1024;    // 98

    hipMemsetAsync(cnt, 0, NNODES * sizeof(int), stream);

    k_pack<<<1, 256, 0, stream>>>(W, attn_l, attn_r, Wb);
    k_gemm_mfma<<<512, 256, 0, stream>>>(h, Wb, z, el, er);

    k_hist<<<(NEDGES + 255) / 256, 256, 0, stream>>>(dst, cnt);
    kscan1<<<SCAN_BLOCKS, 1024, 0, stream>>>(cnt, inc, bsum);
    kscan2<<<1, 128, 0, stream>>>(bsum, SCAN_BLOCKS);
    kscan3<<<SCAN_BLOCKS, 1024, 0, stream>>>(cnt, inc, bsum, offs, cursor);
    k_scatter<<<(NEDGES + 255) / 256, 256, 0, stream>>>(src, dst, cursor, esrc);

    k_agg<<<(NNODES * 64 + 255) / 256, 256, 0, stream>>>(offs, esrc, el, er, z, o, out);
}